// Round 11
// baseline (6849.016 us; speedup 1.0000x reference)
//
#include <hip/hip_runtime.h>
#include <hip/hip_bf16.h>
#include <math.h>

#define WS_B 64
#define WS_S 197
#define WS_D 768
#define WS_NH 12
#define WS_L 12
#define WS_MLP 3072
#define WS_OUT 1000
#define WS_IND 768
#define WS_NPAT 196
#define SP 208      // S padded to 13*16
#define JP 224      // PV K-dim padded to 7*32

typedef __attribute__((ext_vector_type(8))) short bf16x8;
typedef __attribute__((ext_vector_type(4))) short s16x4;
typedef __attribute__((ext_vector_type(4))) float f32x4;

static __device__ __forceinline__ float bf2f(short s) {
    unsigned u = ((unsigned)(unsigned short)s) << 16;
    return __builtin_bit_cast(float, u);
}
static __device__ __forceinline__ short f2bf(float f) {
    unsigned u = __builtin_bit_cast(unsigned, f);
    u = (u + 0x7FFF + ((u >> 16) & 1)) >> 16;
    return (short)u;
}

// bijective XCD remap (m204): contiguous newid chunk per XCD
static __device__ __forceinline__ int xcd_remap(int wg, int nwg) {
    int q = nwg >> 3, r = nwg & 7;
    int xcd = wg & 7, idx = wg >> 3;
    return (xcd < r ? xcd * (q + 1) : r * (q + 1) + (xcd - r) * q) + idx;
}

// ------------------------------------------------- weight transpose to bf16
// W fp32 [L][K][N] row-major -> Wh bf16 [L][N][K]; layer = blockIdx.y
__global__ __launch_bounds__(256) void wconv_kernel(
    const float* __restrict__ W, short* __restrict__ Wh, int K, int N)
{
    const int l = blockIdx.y;
    const float* Wl = W + (size_t)l * K * N;
    short* Whl = Wh + (size_t)l * N * K;
    int idx = blockIdx.x * 256 + threadIdx.x;
    int total = (K >> 3) * N;
    if (idx >= total) return;
    int n = idx % N, k8 = idx / N, k0 = k8 << 3;
    short hi[8];
#pragma unroll
    for (int j = 0; j < 8; ++j) hi[j] = f2bf(Wl[(size_t)(k0 + j) * N + n]);
    *(bf16x8*)(Whl + (size_t)n * K + k0) = *(bf16x8*)hi;
}

// ------------------------------------------------- MFMA GEMM (bf16 in, fp32 acc)
// C[M,N] = act(A[M,K] @ B[K,N] + bias) (+ res) ; B stored [N][K] bf16
// Depth-1 dbuf, wait moved to TOP of next iter (full-iter latency cover):
//   iter t: vmcnt(0) [tile t landed, ~free] ; s_barrier ; STAGE(t+1) ; compute t
__global__ __launch_bounds__(256) void mfma_gemm(
    const short* __restrict__ A, int lda,
    const short* __restrict__ Bh,
    const float* __restrict__ bias, const float* __restrict__ res,
    float* __restrict__ outF, short* __restrict__ outH, int ldc,
    int M, int N, int K, int act)
{
    __shared__ short lds[32768];   // A: slot*8192 ; B: 16384 + slot*8192

    const int tid = threadIdx.x;
    const int w = tid >> 6, lane = tid & 63;
    const int nwg = gridDim.x * gridDim.y;
    int wg = blockIdx.y * gridDim.x + blockIdx.x;
    wg = xcd_remap(wg, nwg);
    const int bm = (wg / gridDim.x) * 128, bn = (wg % gridDim.x) * 128;
    const int wm = (w >> 1) * 64, wn = (w & 1) * 64;
    const int lr = lane & 15, lq = lane >> 4;

    f32x4 acc[4][4];
#pragma unroll
    for (int i = 0; i < 4; ++i)
#pragma unroll
        for (int j = 0; j < 4; ++j) acc[i][j] = (f32x4){0.f, 0.f, 0.f, 0.f};

    int aoff[2][4], boff[2][4];
#pragma unroll
    for (int ks = 0; ks < 2; ++ks)
#pragma unroll
        for (int f = 0; f < 4; ++f) {
            int r = wm + f * 16 + lr;
            aoff[ks][f] = r * 64 + (((ks * 4 + lq) ^ (lr & 7)) << 3);
            int rn = wn + f * 16 + lr;
            boff[ks][f] = rn * 64 + (((ks * 4 + lq) ^ (lr & 7)) << 3);
        }

    // hoisted per-thread staging base addresses (k0 added per iter)
    const short* gaB[4];
    const short* gbB[4];
    int ldsb[4];
#pragma unroll
    for (int i = 0; i < 4; ++i) {
        int chunk = w * 64 + i * 256 + lane;
        int row = chunk >> 3, c = chunk & 7;
        int cs = c ^ (row & 7);
        int arow = bm + row; if (arow >= M) arow = M - 1;
        gaB[i] = A + (size_t)arow * lda + cs * 8;
        gbB[i] = Bh + (size_t)(bn + row) * K + cs * 8;
        ldsb[i] = chunk * 8;
    }

    const int nt = K >> 6;

    auto STAGE = [&](int kt, int slot) {
        const int k0 = kt << 6;
        const int sb = slot * 8192;
#pragma unroll
        for (int i = 0; i < 4; ++i) {
            __builtin_amdgcn_global_load_lds(
                (const __attribute__((address_space(1))) void*)(gaB[i] + k0),
                (__attribute__((address_space(3))) void*)(lds + sb + ldsb[i]), 16, 0, 0);
            __builtin_amdgcn_global_load_lds(
                (const __attribute__((address_space(1))) void*)(gbB[i] + k0),
                (__attribute__((address_space(3))) void*)(lds + 16384 + sb + ldsb[i]), 16, 0, 0);
        }
    };

    STAGE(0, 0);

    for (int t = 0; t < nt; ++t) {
        // tile t's loads were issued a full iteration ago (except t=0) -> near-free
        asm volatile("s_waitcnt vmcnt(0)" ::: "memory");
        // each wave drained ITS OWN loads before this barrier, so barrier-release
        // implies ALL waves' tile-t loads have landed; also makes slot (t+1)&1
        // (read during iter t-1) safe to overwrite.
        asm volatile("s_barrier" ::: "memory");

        if (t + 1 < nt) STAGE(t + 1, (t + 1) & 1);   // full-iter cover under compute t

        const short* Ab = &lds[(t & 1) * 8192];
        const short* Bb = &lds[16384 + (t & 1) * 8192];
#pragma unroll
        for (int ks = 0; ks < 2; ++ks) {
            bf16x8 av[4], bv[4];
#pragma unroll
            for (int f = 0; f < 4; ++f) av[f] = *(const bf16x8*)&Ab[aoff[ks][f]];
#pragma unroll
            for (int f = 0; f < 4; ++f) bv[f] = *(const bf16x8*)&Bb[boff[ks][f]];
#pragma unroll
            for (int fm = 0; fm < 4; ++fm)
#pragma unroll
                for (int fn = 0; fn < 4; ++fn)
                    acc[fm][fn] = __builtin_amdgcn_mfma_f32_16x16x32_bf16(
                        av[fm], bv[fn], acc[fm][fn], 0, 0, 0);
        }
        // no trailing barrier: next iter's top vmcnt+barrier provides it
    }

#pragma unroll
    for (int fm = 0; fm < 4; ++fm)
#pragma unroll
        for (int fn = 0; fn < 4; ++fn) {
            int gc = bn + wn + fn * 16 + lr;
            float bvs = bias ? bias[gc] : 0.f;
            int grb = bm + wm + fm * 16 + lq * 4;
#pragma unroll
            for (int r = 0; r < 4; ++r) {
                int gr = grb + r;
                if (gr >= M) continue;
                float v = acc[fm][fn][r] + bvs;
                if (act == 1) v = 0.5f * v * (1.f + erff(v * 0.70710678118654752440f));
                if (res) v += res[(size_t)gr * ldc + gc];
                if (outF) outF[(size_t)gr * ldc + gc] = v;
                else      outH[(size_t)gr * ldc + gc] = f2bf(v);
            }
        }
}

// ------------------------------------------------- MFMA attention
// qkv bf16 [B*S][2304] (head h: q +h*192, k +h*192+64, v +h*192+128)
// o bf16 [B*S][768]
__global__ __launch_bounds__(256) void attn_kernel(
    const short* __restrict__ qkv, short* __restrict__ o)
{
    __shared__ short Qs[SP * 64];       // [q][64], chunk c stored at c^(q&7)
    __shared__ short Ks[SP * 64];       // [j][64], same swizzle
    __shared__ short Vt[64 * 256];      // [d][j(224 pad, stride 256)], chunk cj^(d&7)
    __shared__ short Ps[4][16 * 256];   // per-wave P[qr][j], chunk cj^(qr&7)

    const int bh = blockIdx.x;
    const int n = bh / WS_NH, h = bh % WS_NH;
    const short* base = qkv + (size_t)n * WS_S * 2304 + h * 192;
    const int tid = threadIdx.x;
    const int w = tid >> 6, lane = tid & 63;
    const int lr = lane & 15, lq = lane >> 4;

    // zero this wave's P buffer (covers j-pad 208..223)
    const bf16x8 z8 = {0, 0, 0, 0, 0, 0, 0, 0};
    for (int i = lane; i < 512; i += 64) *(bf16x8*)&Ps[w][i * 8] = z8;

    // stage Q, K (rows >=197 zeroed)
    for (int u = tid; u < SP * 8; u += 256) {
        int row = u >> 3, c = u & 7;
        int cs = c ^ (row & 7);
        bf16x8 vq = z8, vk = z8;
        if (row < WS_S) {
            const short* rp = base + (size_t)row * 2304;
            vq = *(const bf16x8*)(rp + cs * 8);
            vk = *(const bf16x8*)(rp + 64 + cs * 8);
        }
        *(bf16x8*)&Qs[row * 64 + c * 8] = vq;
        *(bf16x8*)&Ks[row * 64 + c * 8] = vk;
    }

    // stage V transposed: vectorized 16B row loads, transposed scalar LDS scatter
#pragma unroll
    for (int pass = 0; pass < 7; ++pass) {
        int r = pass * 32 + (tid >> 3);     // 0..223
        int c = tid & 7;
        bf16x8 v = z8;
        if (r < WS_S) v = *(const bf16x8*)(base + (size_t)r * 2304 + 128 + c * 8);
#pragma unroll
        for (int e = 0; e < 8; ++e) {
            int d = c * 8 + e;
            Vt[d * 256 + ((((r >> 3)) ^ (d & 7)) << 3) + (r & 7)] = v[e];
        }
    }
    __syncthreads();

    for (int qt = w; qt < 13; qt += 4) {
        // swapped QK^T: D = K·Q^T, lane owns q-col = qt*16+lr
        bf16x8 qv[2];
#pragma unroll
        for (int ks = 0; ks < 2; ++ks)
            qv[ks] = *(const bf16x8*)&Qs[(qt * 16 + lr) * 64 + (((ks * 4 + lq) ^ (lr & 7)) << 3)];
        f32x4 acc[13];
#pragma unroll
        for (int jt = 0; jt < 13; ++jt) acc[jt] = (f32x4){0.f, 0.f, 0.f, 0.f};
#pragma unroll
        for (int jt = 0; jt < 13; ++jt)
#pragma unroll
            for (int ks = 0; ks < 2; ++ks) {
                bf16x8 kv = *(const bf16x8*)&Ks[(jt * 16 + lr) * 64 + (((ks * 4 + lq) ^ (lr & 7)) << 3)];
                acc[jt] = __builtin_amdgcn_mfma_f32_16x16x32_bf16(kv, qv[ks], acc[jt], 0, 0, 0);
            }

        // softmax over j (lane-local 52 values + 2 shuffles across lq groups)
        float s[13][4];
        float m = -1e30f;
#pragma unroll
        for (int jt = 0; jt < 13; ++jt)
#pragma unroll
            for (int r = 0; r < 4; ++r) {
                int j = jt * 16 + lq * 4 + r;
                float v = acc[jt][r] * 0.125f;
                s[jt][r] = v;
                if (j < WS_S) m = fmaxf(m, v);
            }
        m = fmaxf(m, __shfl_xor(m, 16));
        m = fmaxf(m, __shfl_xor(m, 32));
        float sum = 0.f;
#pragma unroll
        for (int jt = 0; jt < 13; ++jt)
#pragma unroll
            for (int r = 0; r < 4; ++r) {
                int j = jt * 16 + lq * 4 + r;
                float e = (j < WS_S) ? __expf(s[jt][r] - m) : 0.f;
                s[jt][r] = e;
                sum += e;
            }
        sum += __shfl_xor(sum, 16);
        sum += __shfl_xor(sum, 32);
        float inv = (sum > 0.f) ? 1.f / sum : 0.f;

        // write P rows (q_local = lr), r-pairs packed as b32
#pragma unroll
        for (int jt = 0; jt < 13; ++jt) {
            int jb = jt * 16 + lq * 4;
            int cj = jb >> 3, e = jb & 7;
            int off = lr * 256 + ((cj ^ (lr & 7)) << 3) + e;
            unsigned p01 = (unsigned)(unsigned short)f2bf(s[jt][0] * inv) |
                           ((unsigned)(unsigned short)f2bf(s[jt][1] * inv) << 16);
            unsigned p23 = (unsigned)(unsigned short)f2bf(s[jt][2] * inv) |
                           ((unsigned)(unsigned short)f2bf(s[jt][3] * inv) << 16);
            *(unsigned*)&Ps[w][off] = p01;
            *(unsigned*)&Ps[w][off + 2] = p23;
        }
        __builtin_amdgcn_s_waitcnt(0);   // drain lds writes (within-wave)

        // PV: O = P @ V (K = 224)
        bf16x8 pa[7];
#pragma unroll
        for (int ks = 0; ks < 7; ++ks)
            pa[ks] = *(const bf16x8*)&Ps[w][lr * 256 + (((ks * 4 + lq) ^ (lr & 7)) << 3)];
#pragma unroll
        for (int dt = 0; dt < 4; ++dt) {
            f32x4 oacc = (f32x4){0.f, 0.f, 0.f, 0.f};
#pragma unroll
            for (int ks = 0; ks < 7; ++ks) {
                bf16x8 vb = *(const bf16x8*)&Vt[(dt * 16 + lr) * 256 + (((ks * 4 + lq) ^ (lr & 7)) << 3)];
                oacc = __builtin_amdgcn_mfma_f32_16x16x32_bf16(pa[ks], vb, oacc, 0, 0, 0);
            }
#pragma unroll
            for (int r = 0; r < 4; ++r) {
                int qg = qt * 16 + lq * 4 + r;
                if (qg < WS_S)
                    o[((size_t)n * WS_S + qg) * WS_D + h * 64 + dt * 16 + lr] = f2bf(oacc[r]);
            }
        }
    }
}

// ------------------------------------------------- head (fp32, latency-friendly)
__global__ __launch_bounds__(256) void head_kernel(
    const float* __restrict__ x, const float* __restrict__ W,
    const float* __restrict__ bias, float* __restrict__ out)
{
    int c = blockIdx.x * 16 + (threadIdx.x & 15);
    int m = blockIdx.y * 16 + (threadIdx.x >> 4);
    if (c >= WS_OUT) return;
    const float* xr = x + (size_t)m * (WS_S * WS_D);
    float acc = bias[c];
    for (int k = 0; k < WS_D; ++k)
        acc = fmaf(xr[k], W[(size_t)k * WS_OUT + c], acc);
    out[(size_t)m * WS_OUT + c] = acc;
}

// ------------------------------------------------- LayerNorm (wave-per-row, fp32 in, bf16 out)
__global__ __launch_bounds__(256) void ln_kernel(
    const float* __restrict__ x, const float* __restrict__ g,
    const float* __restrict__ b, short* __restrict__ y)
{
    const int row = blockIdx.x * 4 + (threadIdx.x >> 6);
    const int lane = threadIdx.x & 63;
    const float* xr = x + (size_t)row * WS_D;
    float4 v0 = *(const float4*)(xr + lane * 4);
    float4 v1 = *(const float4*)(xr + 256 + lane * 4);
    float4 v2 = *(const float4*)(xr + 512 + lane * 4);
    float s = v0.x + v0.y + v0.z + v0.w + v1.x + v1.y + v1.z + v1.w
            + v2.x + v2.y + v2.z + v2.w;
    float q = v0.x * v0.x + v0.y * v0.y + v0.z * v0.z + v0.w * v0.w
            + v1.x * v1.x + v1.y * v1.y + v1.z * v1.z + v1.w * v1.w
            + v2.x * v2.x + v2.y * v2.y + v2.z * v2.z + v2.w * v2.w;
#pragma unroll
    for (int off = 32; off > 0; off >>= 1) {
        s += __shfl_xor(s, off);
        q += __shfl_xor(q, off);
    }
    const float mean = s * (1.f / WS_D);
    const float var = q * (1.f / WS_D) - mean * mean;
    const float rstd = rsqrtf(var + 1e-5f);
    short* yr = y + (size_t)row * WS_D;
#pragma unroll
    for (int c = 0; c < 3; ++c) {
        int o = c * 256 + lane * 4;
        float4 v = (c == 0) ? v0 : (c == 1) ? v1 : v2;
        float4 gv = *(const float4*)(g + o);
        float4 bv = *(const float4*)(b + o);
        s16x4 ov;
        ov[0] = f2bf((v.x - mean) * rstd * gv.x + bv.x);
        ov[1] = f2bf((v.y - mean) * rstd * gv.y + bv.y);
        ov[2] = f2bf((v.z - mean) * rstd * gv.z + bv.z);
        ov[3] = f2bf((v.w - mean) * rstd * gv.w + bv.w);
        *(s16x4*)(yr + o) = ov;
    }
}

// ------------------------------------------------- small utils
__global__ void pe_kernel(float* __restrict__ pe)
{
    int idx = blockIdx.x * 256 + threadIdx.x;
    if (idx >= WS_S * WS_D) return;
    int s = idx / WS_D, j = idx % WS_D;
    float expo = (float)(j & ~1) / (float)WS_D;
    float angle = (float)s * powf(10000.f, -expo);
    pe[idx] = (j & 1) ? cosf(angle) : sinf(angle);
}

__global__ void patchify_kernel(const float* __restrict__ img, short* __restrict__ p)
{
    int idx = blockIdx.x * 256 + threadIdx.x;
    const int total = WS_B * WS_NPAT * WS_IND;
    if (idx >= total) return;
    int pid = idx / WS_IND;
    int e = idx % WS_IND;
    int n = pid / WS_NPAT, patch = pid % WS_NPAT;
    int c = e >> 8, r = e & 255;
    int iy = r >> 4, ix = r & 15;
    int py = patch / 14, px = patch % 14;
    p[idx] = f2bf(img[(((size_t)n * 3 + c) * 224 + py * 16 + iy) * 224 + px * 16 + ix]);
}

__global__ void assemble_kernel(const float* __restrict__ tok, const float* __restrict__ cls,
                                const float* __restrict__ pe, float* __restrict__ x)
{
    int idx = blockIdx.x * 256 + threadIdx.x;
    const int total = WS_B * WS_S * WS_D;
    if (idx >= total) return;
    int row = idx / WS_D, d = idx % WS_D;
    int n = row / WS_S, s = row % WS_S;
    float v = (s == 0) ? cls[d] : tok[((size_t)n * WS_NPAT + (s - 1)) * WS_D + d];
    x[idx] = v + pe[s * WS_D + d];
}

__global__ __launch_bounds__(256) void softmax1000_kernel(
    const float* __restrict__ logits, float* __restrict__ out)
{
    __shared__ float rmax[4], rsum[4];
    const int row = blockIdx.x;
    const int tid = threadIdx.x;
    const float* lr = logits + (size_t)row * WS_OUT;
    float v[4];
    float mx = -INFINITY;
#pragma unroll
    for (int i = 0; i < 4; ++i) {
        int c = tid + i * 256;
        v[i] = (c < WS_OUT) ? lr[c] : -INFINITY;
        mx = fmaxf(mx, v[i]);
    }
#pragma unroll
    for (int off = 32; off > 0; off >>= 1) mx = fmaxf(mx, __shfl_xor(mx, off));
    if ((tid & 63) == 0) rmax[tid >> 6] = mx;
    __syncthreads();
    mx = fmaxf(fmaxf(rmax[0], rmax[1]), fmaxf(rmax[2], rmax[3]));
    float sum = 0.f;
#pragma unroll
    for (int i = 0; i < 4; ++i) {
        int c = tid + i * 256;
        v[i] = (c < WS_OUT) ? expf(v[i] - mx) : 0.f;
        sum += v[i];
    }
#pragma unroll
    for (int off = 32; off > 0; off >>= 1) sum += __shfl_xor(sum, off);
    if ((tid & 63) == 0) rsum[tid >> 6] = sum;
    __syncthreads();
    sum = rsum[0] + rsum[1] + rsum[2] + rsum[3];
    const float inv = 1.f / sum;
#pragma unroll
    for (int i = 0; i < 4; ++i) {
        int c = tid + i * 256;
        if (c < WS_OUT) out[(size_t)row * WS_OUT + c] = v[i] * inv;
    }
}

// ------------------------------------------------- launch
extern "C" void kernel_launch(void* const* d_in, const int* in_sizes, int n_in,
                              void* d_out, int out_size, void* d_ws, size_t ws_size,
                              hipStream_t stream)
{
    const float* images = (const float*)d_in[0];
    const float* lm_w   = (const float*)d_in[1];
    const float* lm_b   = (const float*)d_in[2];
    const float* cls    = (const float*)d_in[3];
    const float* ln1_g  = (const float*)d_in[4];
    const float* ln1_b  = (const float*)d_in[5];
    const float* qkv_w  = (const float*)d_in[6];
    const float* qkv_b  = (const float*)d_in[7];
    const float* out_w  = (const float*)d_in[8];
    const float* out_b  = (const float*)d_in[9];
    const float* ln2_g  = (const float*)d_in[10];
    const float* ln2_b  = (const float*)d_in[11];
    const float* mlp1_w = (const float*)d_in[12];
    const float* mlp1_b = (const float*)d_in[13];
    const float* mlp2_w = (const float*)d_in[14];
    const float* mlp2_b = (const float*)d_in[15];
    const float* head_w = (const float*)d_in[16];
    const float* head_b = (const float*)d_in[17];

    const int ROWS = WS_B * WS_S;          // 12608
    char* wsb = (char*)d_ws;
    size_t off = 0;
    auto alloc = [&](size_t bytes) {
        void* p = wsb + off;
        off += (bytes + 255) & ~(size_t)255;
        return p;
    };
    float* pe     = (float*)alloc((size_t)WS_S * WS_D * 4);
    float* x      = (float*)alloc((size_t)ROWS * WS_D * 4);
    short* xh     = (short*)alloc((size_t)ROWS * WS_D * 2);
    short* qkvh   = (short*)alloc((size_t)ROWS * 2304 * 2);
    short* oh     = (short*)alloc((size_t)ROWS * WS_D * 2);
    short* hh     = (short*)alloc((size_t)ROWS * WS_MLP * 2);
    float* logits = (float*)alloc((size_t)WS_B * WS_OUT * 4);
    short* ph     = (short*)alloc((size_t)WS_B * WS_NPAT * WS_IND * 2);
    // all-layer converted weights (bf16, [N][K] per layer)
    short* qW_all  = (short*)alloc((size_t)WS_L * WS_D * 2304 * 2);
    short* oW_all  = (short*)alloc((size_t)WS_L * WS_D * WS_D * 2);
    short* m1W_all = (short*)alloc((size_t)WS_L * WS_D * WS_MLP * 2);
    short* m2W_all = (short*)alloc((size_t)WS_L * WS_MLP * WS_D * 2);
    short* lmWh    = (short*)alloc((size_t)WS_IND * WS_D * 2);
    float* tok  = (float*)hh;   // overlay (pre-loop only): 38.5 MB < hh

    pe_kernel<<<(WS_S * WS_D + 255) / 256, 256, 0, stream>>>(pe);
    patchify_kernel<<<(WS_B * WS_NPAT * WS_IND + 255) / 256, 256, 0, stream>>>(images, ph);
    // one-time conversion of ALL weights
    wconv_kernel<<<dim3((WS_IND / 8 * WS_D + 255) / 256, 1), 256, 0, stream>>>(lm_w, lmWh, WS_IND, WS_D);
    wconv_kernel<<<dim3((WS_D / 8 * 2304 + 255) / 256, WS_L), 256, 0, stream>>>(qkv_w, qW_all, WS_D, 2304);
    wconv_kernel<<<dim3((WS_D / 8 * WS_D + 255) / 256, WS_L), 256, 0, stream>>>(out_w, oW_all, WS_D, WS_D);
    wconv_kernel<<<dim3((WS_D / 8 * WS_MLP + 255) / 256, WS_L), 256, 0, stream>>>(mlp1_w, m1W_all, WS_D, WS_MLP);
    wconv_kernel<<<dim3((WS_MLP / 8 * WS_D + 255) / 256, WS_L), 256, 0, stream>>>(mlp2_w, m2W_all, WS_MLP, WS_D);

    // tok = patches @ lm_w + lm_b  (M=12544, N=768, K=768)
    mfma_gemm<<<dim3(6, 98), 256, 0, stream>>>(
        ph, WS_IND, lmWh, lm_b, nullptr, tok, nullptr, WS_D,
        WS_B * WS_NPAT, WS_D, WS_IND, 0);
    assemble_kernel<<<(WS_B * WS_S * WS_D + 255) / 256, 256, 0, stream>>>(tok, cls, pe, x);

    for (int l = 0; l < WS_L; ++l) {
        ln_kernel<<<ROWS / 4, 256, 0, stream>>>(x, ln1_g + l * WS_D, ln1_b + l * WS_D, xh);
        mfma_gemm<<<dim3(18, 99), 256, 0, stream>>>(
            xh, WS_D, qW_all + (size_t)l * WS_D * 2304, qkv_b + l * 2304,
            nullptr, nullptr, qkvh, 2304, ROWS, 2304, WS_D, 0);
        attn_kernel<<<WS_B * WS_NH, 256, 0, stream>>>(qkvh, oh);
        mfma_gemm<<<dim3(6, 99), 256, 0, stream>>>(
            oh, WS_D, oW_all + (size_t)l * WS_D * WS_D, out_b + l * WS_D,
            x, x, nullptr, WS_D, ROWS, WS_D, WS_D, 0);
        ln_kernel<<<ROWS / 4, 256, 0, stream>>>(x, ln2_g + l * WS_D, ln2_b + l * WS_D, xh);
        mfma_gemm<<<dim3(24, 99), 256, 0, stream>>>(
            xh, WS_D, m1W_all + (size_t)l * WS_D * WS_MLP, mlp1_b + l * WS_MLP,
            nullptr, nullptr, hh, WS_MLP, ROWS, WS_MLP, WS_D, 1);
        mfma_gemm<<<dim3(6, 99), 256, 0, stream>>>(
            hh, WS_MLP, m2W_all + (size_t)l * WS_MLP * WS_D, mlp2_b + l * WS_D,
            x, x, nullptr, WS_D, ROWS, WS_D, WS_MLP, 0);
    }

    head_kernel<<<dim3((WS_OUT + 15) / 16, 4), 256, 0, stream>>>(x, head_w, head_b, logits);
    softmax1000_kernel<<<WS_B, 256, 0, stream>>>(logits, (float*)d_out);
}

// Round 12
// 6158.728 us; speedup vs baseline: 1.1121x; 1.1121x over previous
//
#include <hip/hip_runtime.h>
#include <hip/hip_bf16.h>
#include <math.h>

#define WS_B 64
#define WS_S 197
#define WS_D 768
#define WS_NH 12
#define WS_L 12
#define WS_MLP 3072
#define WS_OUT 1000
#define WS_IND 768
#define WS_NPAT 196
#define SP 208      // S padded to 13*16
#define JP 224      // PV K-dim padded to 7*32

typedef __attribute__((ext_vector_type(8))) short bf16x8;
typedef __attribute__((ext_vector_type(4))) short s16x4;
typedef __attribute__((ext_vector_type(4))) float f32x4;

static __device__ __forceinline__ float bf2f(short s) {
    unsigned u = ((unsigned)(unsigned short)s) << 16;
    return __builtin_bit_cast(float, u);
}
static __device__ __forceinline__ short f2bf(float f) {
    unsigned u = __builtin_bit_cast(unsigned, f);
    u = (u + 0x7FFF + ((u >> 16) & 1)) >> 16;
    return (short)u;
}

// bijective XCD remap (m204): contiguous newid chunk per XCD
static __device__ __forceinline__ int xcd_remap(int wg, int nwg) {
    int q = nwg >> 3, r = nwg & 7;
    int xcd = wg & 7, idx = wg >> 3;
    return (xcd < r ? xcd * (q + 1) : r * (q + 1) + (xcd - r) * q) + idx;
}

// ------------------------------------------------- weight transpose to bf16
// W fp32 [L][K][N] row-major -> Wh bf16 [L][N][K]; layer = blockIdx.y
__global__ __launch_bounds__(256) void wconv_kernel(
    const float* __restrict__ W, short* __restrict__ Wh, int K, int N)
{
    const int l = blockIdx.y;
    const float* Wl = W + (size_t)l * K * N;
    short* Whl = Wh + (size_t)l * N * K;
    int idx = blockIdx.x * 256 + threadIdx.x;
    int total = (K >> 3) * N;
    if (idx >= total) return;
    int n = idx % N, k8 = idx / N, k0 = k8 << 3;
    short hi[8];
#pragma unroll
    for (int j = 0; j < 8; ++j) hi[j] = f2bf(Wl[(size_t)(k0 + j) * N + n]);
    *(bf16x8*)(Whl + (size_t)n * K + k0) = *(bf16x8*)hi;
}

// ------------------------------------------------- MFMA GEMM (bf16 in, fp32 acc)
// C[M,N] = act(A[M,K] @ B[K,N] + bias) (+ res) ; B stored [N][K] bf16
// Proven 5.84ms structure: 128^2 tile, 32KB single-buffer LDS, 4 blocks/CU TLP.
__global__ __launch_bounds__(256) void mfma_gemm(
    const short* __restrict__ A, int lda,
    const short* __restrict__ Bh,
    const float* __restrict__ bias, const float* __restrict__ res,
    float* __restrict__ outF, short* __restrict__ outH, int ldc,
    int M, int N, int K, int act)
{
    __shared__ short As[128 * 64];
    __shared__ short Bs[128 * 64];

    const int tid = threadIdx.x;
    const int w = tid >> 6, lane = tid & 63;
    const int nwg = gridDim.x * gridDim.y;
    int wg = blockIdx.y * gridDim.x + blockIdx.x;
    wg = xcd_remap(wg, nwg);
    const int bm = (wg / gridDim.x) * 128, bn = (wg % gridDim.x) * 128;
    const int wm = (w >> 1) * 64, wn = (w & 1) * 64;
    const int lr = lane & 15, lq = lane >> 4;

    f32x4 acc[4][4];
#pragma unroll
    for (int i = 0; i < 4; ++i)
#pragma unroll
        for (int j = 0; j < 4; ++j) acc[i][j] = (f32x4){0.f, 0.f, 0.f, 0.f};

    int aoff[2][4], boff[2][4];
#pragma unroll
    for (int ks = 0; ks < 2; ++ks)
#pragma unroll
        for (int f = 0; f < 4; ++f) {
            int r = wm + f * 16 + lr;
            aoff[ks][f] = r * 64 + (((ks * 4 + lq) ^ (lr & 7)) << 3);
            int rn = wn + f * 16 + lr;
            boff[ks][f] = rn * 64 + (((ks * 4 + lq) ^ (lr & 7)) << 3);
        }

    // hoisted per-thread staging base addresses (k0 added per iter)
    const short* gaB[4];
    const short* gbB[4];
    int ldsb[4];
#pragma unroll
    for (int i = 0; i < 4; ++i) {
        int chunk = w * 64 + i * 256 + lane;
        int row = chunk >> 3, c = chunk & 7;
        int cs = c ^ (row & 7);
        int arow = bm + row; if (arow >= M) arow = M - 1;
        gaB[i] = A + (size_t)arow * lda + cs * 8;
        gbB[i] = Bh + (size_t)(bn + row) * K + cs * 8;
        ldsb[i] = chunk * 8;
    }

    for (int k0 = 0; k0 < K; k0 += 64) {
#pragma unroll
        for (int i = 0; i < 4; ++i) {
            __builtin_amdgcn_global_load_lds(
                (const __attribute__((address_space(1))) void*)(gaB[i] + k0),
                (__attribute__((address_space(3))) void*)(As + ldsb[i]), 16, 0, 0);
            __builtin_amdgcn_global_load_lds(
                (const __attribute__((address_space(1))) void*)(gbB[i] + k0),
                (__attribute__((address_space(3))) void*)(Bs + ldsb[i]), 16, 0, 0);
        }
        asm volatile("s_waitcnt vmcnt(0)" ::: "memory");
        __syncthreads();

#pragma unroll
        for (int ks = 0; ks < 2; ++ks) {
            bf16x8 av[4], bv[4];
#pragma unroll
            for (int f = 0; f < 4; ++f) av[f] = *(const bf16x8*)&As[aoff[ks][f]];
#pragma unroll
            for (int f = 0; f < 4; ++f) bv[f] = *(const bf16x8*)&Bs[boff[ks][f]];
#pragma unroll
            for (int fm = 0; fm < 4; ++fm)
#pragma unroll
                for (int fn = 0; fn < 4; ++fn)
                    acc[fm][fn] = __builtin_amdgcn_mfma_f32_16x16x32_bf16(
                        av[fm], bv[fn], acc[fm][fn], 0, 0, 0);
        }
        __syncthreads();
    }

#pragma unroll
    for (int fm = 0; fm < 4; ++fm)
#pragma unroll
        for (int fn = 0; fn < 4; ++fn) {
            int gc = bn + wn + fn * 16 + lr;
            float bvs = bias ? bias[gc] : 0.f;
            int grb = bm + wm + fm * 16 + lq * 4;
#pragma unroll
            for (int r = 0; r < 4; ++r) {
                int gr = grb + r;
                if (gr >= M) continue;
                float v = acc[fm][fn][r] + bvs;
                if (act == 1) v = 0.5f * v * (1.f + erff(v * 0.70710678118654752440f));
                if (res) v += res[(size_t)gr * ldc + gc];
                if (outF) outF[(size_t)gr * ldc + gc] = v;
                else      outH[(size_t)gr * ldc + gc] = f2bf(v);
            }
        }
}

// ------------------------------------------------- 64x128 MFMA GEMM (grid-starved N=768 cases)
// Same contract/algebra; BM=64 -> 2x blocks, 24KB LDS -> 6 blocks/CU.
__global__ __launch_bounds__(256) void mfma_gemm_m64(
    const short* __restrict__ A, int lda,
    const short* __restrict__ Bh,
    const float* __restrict__ bias, const float* __restrict__ res,
    float* __restrict__ outF, short* __restrict__ outH, int ldc,
    int M, int N, int K, int act)
{
    __shared__ short As[64 * 64];
    __shared__ short Bs[128 * 64];

    const int tid = threadIdx.x;
    const int w = tid >> 6, lane = tid & 63;
    const int nwg = gridDim.x * gridDim.y;
    int wg = blockIdx.y * gridDim.x + blockIdx.x;
    wg = xcd_remap(wg, nwg);
    const int bm = (wg / gridDim.x) * 64, bn = (wg % gridDim.x) * 128;
    const int wm = (w >> 1) * 32, wn = (w & 1) * 64;
    const int lr = lane & 15, lq = lane >> 4;

    f32x4 acc[2][4];
#pragma unroll
    for (int i = 0; i < 2; ++i)
#pragma unroll
        for (int j = 0; j < 4; ++j) acc[i][j] = (f32x4){0.f, 0.f, 0.f, 0.f};

    int aoff[2][2], boff[2][4];
#pragma unroll
    for (int ks = 0; ks < 2; ++ks) {
#pragma unroll
        for (int f = 0; f < 2; ++f) {
            int r = wm + f * 16 + lr;              // wm∈{0,32}: r&7 == lr&7
            aoff[ks][f] = r * 64 + (((ks * 4 + lq) ^ (lr & 7)) << 3);
        }
#pragma unroll
        for (int f = 0; f < 4; ++f) {
            int rn = wn + f * 16 + lr;
            boff[ks][f] = rn * 64 + (((ks * 4 + lq) ^ (lr & 7)) << 3);
        }
    }

    // staging: A = 512 chunks (2/thread), B = 1024 chunks (4/thread)
    const short* gaB[2];
    int ldsbA[2];
#pragma unroll
    for (int i = 0; i < 2; ++i) {
        int chunk = i * 256 + tid;
        int row = chunk >> 3, c = chunk & 7;
        int cs = c ^ (row & 7);
        int arow = bm + row; if (arow >= M) arow = M - 1;
        gaB[i] = A + (size_t)arow * lda + cs * 8;
        ldsbA[i] = chunk * 8;
    }
    const short* gbB[4];
    int ldsbB[4];
#pragma unroll
    for (int i = 0; i < 4; ++i) {
        int chunk = i * 256 + tid;
        int row = chunk >> 3, c = chunk & 7;
        int cs = c ^ (row & 7);
        gbB[i] = Bh + (size_t)(bn + row) * K + cs * 8;
        ldsbB[i] = chunk * 8;
    }

    for (int k0 = 0; k0 < K; k0 += 64) {
#pragma unroll
        for (int i = 0; i < 2; ++i)
            __builtin_amdgcn_global_load_lds(
                (const __attribute__((address_space(1))) void*)(gaB[i] + k0),
                (__attribute__((address_space(3))) void*)(As + ldsbA[i]), 16, 0, 0);
#pragma unroll
        for (int i = 0; i < 4; ++i)
            __builtin_amdgcn_global_load_lds(
                (const __attribute__((address_space(1))) void*)(gbB[i] + k0),
                (__attribute__((address_space(3))) void*)(Bs + ldsbB[i]), 16, 0, 0);
        asm volatile("s_waitcnt vmcnt(0)" ::: "memory");
        __syncthreads();

#pragma unroll
        for (int ks = 0; ks < 2; ++ks) {
            bf16x8 av[2], bv[4];
#pragma unroll
            for (int f = 0; f < 2; ++f) av[f] = *(const bf16x8*)&As[aoff[ks][f]];
#pragma unroll
            for (int f = 0; f < 4; ++f) bv[f] = *(const bf16x8*)&Bs[boff[ks][f]];
#pragma unroll
            for (int fm = 0; fm < 2; ++fm)
#pragma unroll
                for (int fn = 0; fn < 4; ++fn)
                    acc[fm][fn] = __builtin_amdgcn_mfma_f32_16x16x32_bf16(
                        av[fm], bv[fn], acc[fm][fn], 0, 0, 0);
        }
        __syncthreads();
    }

#pragma unroll
    for (int fm = 0; fm < 2; ++fm)
#pragma unroll
        for (int fn = 0; fn < 4; ++fn) {
            int gc = bn + wn + fn * 16 + lr;
            float bvs = bias ? bias[gc] : 0.f;
            int grb = bm + wm + fm * 16 + lq * 4;
#pragma unroll
            for (int r = 0; r < 4; ++r) {
                int gr = grb + r;
                if (gr >= M) continue;
                float v = acc[fm][fn][r] + bvs;
                if (act == 1) v = 0.5f * v * (1.f + erff(v * 0.70710678118654752440f));
                if (res) v += res[(size_t)gr * ldc + gc];
                if (outF) outF[(size_t)gr * ldc + gc] = v;
                else      outH[(size_t)gr * ldc + gc] = f2bf(v);
            }
        }
}

// ------------------------------------------------- MFMA attention
// qkv bf16 [B*S][2304] (head h: q +h*192, k +h*192+64, v +h*192+128)
// o bf16 [B*S][768]
__global__ __launch_bounds__(256) void attn_kernel(
    const short* __restrict__ qkv, short* __restrict__ o)
{
    __shared__ short Qs[SP * 64];       // [q][64], chunk c stored at c^(q&7)
    __shared__ short Ks[SP * 64];       // [j][64], same swizzle
    __shared__ short Vt[64 * 256];      // [d][j(224 pad, stride 256)], chunk cj^(d&7)
    __shared__ short Ps[4][16 * 256];   // per-wave P[qr][j], chunk cj^(qr&7)

    const int bh = blockIdx.x;
    const int n = bh / WS_NH, h = bh % WS_NH;
    const short* base = qkv + (size_t)n * WS_S * 2304 + h * 192;
    const int tid = threadIdx.x;
    const int w = tid >> 6, lane = tid & 63;
    const int lr = lane & 15, lq = lane >> 4;

    // zero this wave's P buffer (covers j-pad 208..223)
    const bf16x8 z8 = {0, 0, 0, 0, 0, 0, 0, 0};
    for (int i = lane; i < 512; i += 64) *(bf16x8*)&Ps[w][i * 8] = z8;

    // stage Q, K (rows >=197 zeroed)
    for (int u = tid; u < SP * 8; u += 256) {
        int row = u >> 3, c = u & 7;
        int cs = c ^ (row & 7);
        bf16x8 vq = z8, vk = z8;
        if (row < WS_S) {
            const short* rp = base + (size_t)row * 2304;
            vq = *(const bf16x8*)(rp + cs * 8);
            vk = *(const bf16x8*)(rp + 64 + cs * 8);
        }
        *(bf16x8*)&Qs[row * 64 + c * 8] = vq;
        *(bf16x8*)&Ks[row * 64 + c * 8] = vk;
    }

    // stage V transposed: vectorized 16B row loads, transposed scalar LDS scatter
#pragma unroll
    for (int pass = 0; pass < 7; ++pass) {
        int r = pass * 32 + (tid >> 3);     // 0..223
        int c = tid & 7;
        bf16x8 v = z8;
        if (r < WS_S) v = *(const bf16x8*)(base + (size_t)r * 2304 + 128 + c * 8);
#pragma unroll
        for (int e = 0; e < 8; ++e) {
            int d = c * 8 + e;
            Vt[d * 256 + ((((r >> 3)) ^ (d & 7)) << 3) + (r & 7)] = v[e];
        }
    }
    __syncthreads();

    for (int qt = w; qt < 13; qt += 4) {
        // swapped QK^T: D = K·Q^T, lane owns q-col = qt*16+lr
        bf16x8 qv[2];
#pragma unroll
        for (int ks = 0; ks < 2; ++ks)
            qv[ks] = *(const bf16x8*)&Qs[(qt * 16 + lr) * 64 + (((ks * 4 + lq) ^ (lr & 7)) << 3)];
        f32x4 acc[13];
#pragma unroll
        for (int jt = 0; jt < 13; ++jt) acc[jt] = (f32x4){0.f, 0.f, 0.f, 0.f};
#pragma unroll
        for (int jt = 0; jt < 13; ++jt)
#pragma unroll
            for (int ks = 0; ks < 2; ++ks) {
                bf16x8 kv = *(const bf16x8*)&Ks[(jt * 16 + lr) * 64 + (((ks * 4 + lq) ^ (lr & 7)) << 3)];
                acc[jt] = __builtin_amdgcn_mfma_f32_16x16x32_bf16(kv, qv[ks], acc[jt], 0, 0, 0);
            }

        // softmax over j (lane-local 52 values + 2 shuffles across lq groups)
        float s[13][4];
        float m = -1e30f;
#pragma unroll
        for (int jt = 0; jt < 13; ++jt)
#pragma unroll
            for (int r = 0; r < 4; ++r) {
                int j = jt * 16 + lq * 4 + r;
                float v = acc[jt][r] * 0.125f;
                s[jt][r] = v;
                if (j < WS_S) m = fmaxf(m, v);
            }
        m = fmaxf(m, __shfl_xor(m, 16));
        m = fmaxf(m, __shfl_xor(m, 32));
        float sum = 0.f;
#pragma unroll
        for (int jt = 0; jt < 13; ++jt)
#pragma unroll
            for (int r = 0; r < 4; ++r) {
                int j = jt * 16 + lq * 4 + r;
                float e = (j < WS_S) ? __expf(s[jt][r] - m) : 0.f;
                s[jt][r] = e;
                sum += e;
            }
        sum += __shfl_xor(sum, 16);
        sum += __shfl_xor(sum, 32);
        float inv = (sum > 0.f) ? 1.f / sum : 0.f;

        // write P rows (q_local = lr), r-pairs packed as b32
#pragma unroll
        for (int jt = 0; jt < 13; ++jt) {
            int jb = jt * 16 + lq * 4;
            int cj = jb >> 3, e = jb & 7;
            int off = lr * 256 + ((cj ^ (lr & 7)) << 3) + e;
            unsigned p01 = (unsigned)(unsigned short)f2bf(s[jt][0] * inv) |
                           ((unsigned)(unsigned short)f2bf(s[jt][1] * inv) << 16);
            unsigned p23 = (unsigned)(unsigned short)f2bf(s[jt][2] * inv) |
                           ((unsigned)(unsigned short)f2bf(s[jt][3] * inv) << 16);
            *(unsigned*)&Ps[w][off] = p01;
            *(unsigned*)&Ps[w][off + 2] = p23;
        }
        __builtin_amdgcn_s_waitcnt(0);   // drain lds writes (within-wave)

        // PV: O = P @ V (K = 224)
        bf16x8 pa[7];
#pragma unroll
        for (int ks = 0; ks < 7; ++ks)
            pa[ks] = *(const bf16x8*)&Ps[w][lr * 256 + (((ks * 4 + lq) ^ (lr & 7)) << 3)];
#pragma unroll
        for (int dt = 0; dt < 4; ++dt) {
            f32x4 oacc = (f32x4){0.f, 0.f, 0.f, 0.f};
#pragma unroll
            for (int ks = 0; ks < 7; ++ks) {
                bf16x8 vb = *(const bf16x8*)&Vt[(dt * 16 + lr) * 256 + (((ks * 4 + lq) ^ (lr & 7)) << 3)];
                oacc = __builtin_amdgcn_mfma_f32_16x16x32_bf16(pa[ks], vb, oacc, 0, 0, 0);
            }
#pragma unroll
            for (int r = 0; r < 4; ++r) {
                int qg = qt * 16 + lq * 4 + r;
                if (qg < WS_S)
                    o[((size_t)n * WS_S + qg) * WS_D + h * 64 + dt * 16 + lr] = f2bf(oacc[r]);
            }
        }
    }
}

// ------------------------------------------------- head (fp32, latency-friendly)
__global__ __launch_bounds__(256) void head_kernel(
    const float* __restrict__ x, const float* __restrict__ W,
    const float* __restrict__ bias, float* __restrict__ out)
{
    int c = blockIdx.x * 16 + (threadIdx.x & 15);
    int m = blockIdx.y * 16 + (threadIdx.x >> 4);
    if (c >= WS_OUT) return;
    const float* xr = x + (size_t)m * (WS_S * WS_D);
    float acc = bias[c];
    for (int k = 0; k < WS_D; ++k)
        acc = fmaf(xr[k], W[(size_t)k * WS_OUT + c], acc);
    out[(size_t)m * WS_OUT + c] = acc;
}

// ------------------------------------------------- LayerNorm (wave-per-row, fp32 in, bf16 out)
__global__ __launch_bounds__(256) void ln_kernel(
    const float* __restrict__ x, const float* __restrict__ g,
    const float* __restrict__ b, short* __restrict__ y)
{
    const int row = blockIdx.x * 4 + (threadIdx.x >> 6);
    const int lane = threadIdx.x & 63;
    const float* xr = x + (size_t)row * WS_D;
    float4 v0 = *(const float4*)(xr + lane * 4);
    float4 v1 = *(const float4*)(xr + 256 + lane * 4);
    float4 v2 = *(const float4*)(xr + 512 + lane * 4);
    float s = v0.x + v0.y + v0.z + v0.w + v1.x + v1.y + v1.z + v1.w
            + v2.x + v2.y + v2.z + v2.w;
    float q = v0.x * v0.x + v0.y * v0.y + v0.z * v0.z + v0.w * v0.w
            + v1.x * v1.x + v1.y * v1.y + v1.z * v1.z + v1.w * v1.w
            + v2.x * v2.x + v2.y * v2.y + v2.z * v2.z + v2.w * v2.w;
#pragma unroll
    for (int off = 32; off > 0; off >>= 1) {
        s += __shfl_xor(s, off);
        q += __shfl_xor(q, off);
    }
    const float mean = s * (1.f / WS_D);
    const float var = q * (1.f / WS_D) - mean * mean;
    const float rstd = rsqrtf(var + 1e-5f);
    short* yr = y + (size_t)row * WS_D;
#pragma unroll
    for (int c = 0; c < 3; ++c) {
        int o = c * 256 + lane * 4;
        float4 v = (c == 0) ? v0 : (c == 1) ? v1 : v2;
        float4 gv = *(const float4*)(g + o);
        float4 bv = *(const float4*)(b + o);
        s16x4 ov;
        ov[0] = f2bf((v.x - mean) * rstd * gv.x + bv.x);
        ov[1] = f2bf((v.y - mean) * rstd * gv.y + bv.y);
        ov[2] = f2bf((v.z - mean) * rstd * gv.z + bv.z);
        ov[3] = f2bf((v.w - mean) * rstd * gv.w + bv.w);
        *(s16x4*)(yr + o) = ov;
    }
}

// ------------------------------------------------- small utils
__global__ void pe_kernel(float* __restrict__ pe)
{
    int idx = blockIdx.x * 256 + threadIdx.x;
    if (idx >= WS_S * WS_D) return;
    int s = idx / WS_D, j = idx % WS_D;
    float expo = (float)(j & ~1) / (float)WS_D;
    float angle = (float)s * powf(10000.f, -expo);
    pe[idx] = (j & 1) ? cosf(angle) : sinf(angle);
}

__global__ void patchify_kernel(const float* __restrict__ img, short* __restrict__ p)
{
    int idx = blockIdx.x * 256 + threadIdx.x;
    const int total = WS_B * WS_NPAT * WS_IND;
    if (idx >= total) return;
    int pid = idx / WS_IND;
    int e = idx % WS_IND;
    int n = pid / WS_NPAT, patch = pid % WS_NPAT;
    int c = e >> 8, r = e & 255;
    int iy = r >> 4, ix = r & 15;
    int py = patch / 14, px = patch % 14;
    p[idx] = f2bf(img[(((size_t)n * 3 + c) * 224 + py * 16 + iy) * 224 + px * 16 + ix]);
}

__global__ void assemble_kernel(const float* __restrict__ tok, const float* __restrict__ cls,
                                const float* __restrict__ pe, float* __restrict__ x)
{
    int idx = blockIdx.x * 256 + threadIdx.x;
    const int total = WS_B * WS_S * WS_D;
    if (idx >= total) return;
    int row = idx / WS_D, d = idx % WS_D;
    int n = row / WS_S, s = row % WS_S;
    float v = (s == 0) ? cls[d] : tok[((size_t)n * WS_NPAT + (s - 1)) * WS_D + d];
    x[idx] = v + pe[s * WS_D + d];
}

__global__ __launch_bounds__(256) void softmax1000_kernel(
    const float* __restrict__ logits, float* __restrict__ out)
{
    __shared__ float rmax[4], rsum[4];
    const int row = blockIdx.x;
    const int tid = threadIdx.x;
    const float* lr = logits + (size_t)row * WS_OUT;
    float v[4];
    float mx = -INFINITY;
#pragma unroll
    for (int i = 0; i < 4; ++i) {
        int c = tid + i * 256;
        v[i] = (c < WS_OUT) ? lr[c] : -INFINITY;
        mx = fmaxf(mx, v[i]);
    }
#pragma unroll
    for (int off = 32; off > 0; off >>= 1) mx = fmaxf(mx, __shfl_xor(mx, off));
    if ((tid & 63) == 0) rmax[tid >> 6] = mx;
    __syncthreads();
    mx = fmaxf(fmaxf(rmax[0], rmax[1]), fmaxf(rmax[2], rmax[3]));
    float sum = 0.f;
#pragma unroll
    for (int i = 0; i < 4; ++i) {
        int c = tid + i * 256;
        v[i] = (c < WS_OUT) ? expf(v[i] - mx) : 0.f;
        sum += v[i];
    }
#pragma unroll
    for (int off = 32; off > 0; off >>= 1) sum += __shfl_xor(sum, off);
    if ((tid & 63) == 0) rsum[tid >> 6] = sum;
    __syncthreads();
    sum = rsum[0] + rsum[1] + rsum[2] + rsum[3];
    const float inv = 1.f / sum;
#pragma unroll
    for (int i = 0; i < 4; ++i) {
        int c = tid + i * 256;
        if (c < WS_OUT) out[(size_t)row * WS_OUT + c] = v[i] * inv;
    }
}

// ------------------------------------------------- launch
extern "C" void kernel_launch(void* const* d_in, const int* in_sizes, int n_in,
                              void* d_out, int out_size, void* d_ws, size_t ws_size,
                              hipStream_t stream)
{
    const float* images = (const float*)d_in[0];
    const float* lm_w   = (const float*)d_in[1];
    const float* lm_b   = (const float*)d_in[2];
    const float* cls    = (const float*)d_in[3];
    const float* ln1_g  = (const float*)d_in[4];
    const float* ln1_b  = (const float*)d_in[5];
    const float* qkv_w  = (const float*)d_in[6];
    const float* qkv_b  = (const float*)d_in[7];
    const float* out_w  = (const float*)d_in[8];
    const float* out_b  = (const float*)d_in[9];
    const float* ln2_g  = (const float*)d_in[10];
    const float* ln2_b  = (const float*)d_in[11];
    const float* mlp1_w = (const float*)d_in[12];
    const float* mlp1_b = (const float*)d_in[13];
    const float* mlp2_w = (const float*)d_in[14];
    const float* mlp2_b = (const float*)d_in[15];
    const float* head_w = (const float*)d_in[16];
    const float* head_b = (const float*)d_in[17];

    const int ROWS = WS_B * WS_S;          // 12608 = 197*64
    char* wsb = (char*)d_ws;
    size_t off = 0;
    auto alloc = [&](size_t bytes) {
        void* p = wsb + off;
        off += (bytes + 255) & ~(size_t)255;
        return p;
    };
    float* pe     = (float*)alloc((size_t)WS_S * WS_D * 4);
    float* x      = (float*)alloc((size_t)ROWS * WS_D * 4);
    short* xh     = (short*)alloc((size_t)ROWS * WS_D * 2);
    short* qkvh   = (short*)alloc((size_t)ROWS * 2304 * 2);
    short* oh     = (short*)alloc((size_t)ROWS * WS_D * 2);
    short* hh     = (short*)alloc((size_t)ROWS * WS_MLP * 2);
    float* logits = (float*)alloc((size_t)WS_B * WS_OUT * 4);
    short* ph     = (short*)alloc((size_t)WS_B * WS_NPAT * WS_IND * 2);
    // all-layer converted weights (bf16, [N][K] per layer)
    short* qW_all  = (short*)alloc((size_t)WS_L * WS_D * 2304 * 2);
    short* oW_all  = (short*)alloc((size_t)WS_L * WS_D * WS_D * 2);
    short* m1W_all = (short*)alloc((size_t)WS_L * WS_D * WS_MLP * 2);
    short* m2W_all = (short*)alloc((size_t)WS_L * WS_MLP * WS_D * 2);
    short* lmWh    = (short*)alloc((size_t)WS_IND * WS_D * 2);
    float* tok  = (float*)hh;   // overlay (pre-loop only): 38.5 MB < hh

    pe_kernel<<<(WS_S * WS_D + 255) / 256, 256, 0, stream>>>(pe);
    patchify_kernel<<<(WS_B * WS_NPAT * WS_IND + 255) / 256, 256, 0, stream>>>(images, ph);
    // one-time conversion of ALL weights
    wconv_kernel<<<dim3((WS_IND / 8 * WS_D + 255) / 256, 1), 256, 0, stream>>>(lm_w, lmWh, WS_IND, WS_D);
    wconv_kernel<<<dim3((WS_D / 8 * 2304 + 255) / 256, WS_L), 256, 0, stream>>>(qkv_w, qW_all, WS_D, 2304);
    wconv_kernel<<<dim3((WS_D / 8 * WS_D + 255) / 256, WS_L), 256, 0, stream>>>(out_w, oW_all, WS_D, WS_D);
    wconv_kernel<<<dim3((WS_D / 8 * WS_MLP + 255) / 256, WS_L), 256, 0, stream>>>(mlp1_w, m1W_all, WS_D, WS_MLP);
    wconv_kernel<<<dim3((WS_MLP / 8 * WS_D + 255) / 256, WS_L), 256, 0, stream>>>(mlp2_w, m2W_all, WS_MLP, WS_D);

    // tok = patches @ lm_w + lm_b  (M=12544=196*64, N=768, K=768)
    mfma_gemm_m64<<<dim3(6, 196), 256, 0, stream>>>(
        ph, WS_IND, lmWh, lm_b, nullptr, tok, nullptr, WS_D,
        WS_B * WS_NPAT, WS_D, WS_IND, 0);
    assemble_kernel<<<(WS_B * WS_S * WS_D + 255) / 256, 256, 0, stream>>>(tok, cls, pe, x);

    for (int l = 0; l < WS_L; ++l) {
        ln_kernel<<<ROWS / 4, 256, 0, stream>>>(x, ln1_g + l * WS_D, ln1_b + l * WS_D, xh);
        mfma_gemm<<<dim3(18, 99), 256, 0, stream>>>(
            xh, WS_D, qW_all + (size_t)l * WS_D * 2304, qkv_b + l * 2304,
            nullptr, nullptr, qkvh, 2304, ROWS, 2304, WS_D, 0);
        attn_kernel<<<WS_B * WS_NH, 256, 0, stream>>>(qkvh, oh);
        mfma_gemm_m64<<<dim3(6, 197), 256, 0, stream>>>(
            oh, WS_D, oW_all + (size_t)l * WS_D * WS_D, out_b + l * WS_D,
            x, x, nullptr, WS_D, ROWS, WS_D, WS_D, 0);
        ln_kernel<<<ROWS / 4, 256, 0, stream>>>(x, ln2_g + l * WS_D, ln2_b + l * WS_D, xh);
        mfma_gemm<<<dim3(24, 99), 256, 0, stream>>>(
            xh, WS_D, m1W_all + (size_t)l * WS_D * WS_MLP, mlp1_b + l * WS_MLP,
            nullptr, nullptr, hh, WS_MLP, ROWS, WS_MLP, WS_D, 1);
        mfma_gemm_m64<<<dim3(6, 197), 256, 0, stream>>>(
            hh, WS_MLP, m2W_all + (size_t)l * WS_MLP * WS_D, mlp2_b + l * WS_D,
            x, x, nullptr, WS_D, ROWS, WS_D, WS_MLP, 0);
    }

    head_kernel<<<dim3((WS_OUT + 15) / 16, 4), 256, 0, stream>>>(x, head_w, head_b, logits);
    softmax1000_kernel<<<WS_B, 256, 0, stream>>>(logits, (float*)d_out);
}

// Round 13
// 5257.485 us; speedup vs baseline: 1.3027x; 1.1714x over previous
//
#include <hip/hip_runtime.h>
#include <hip/hip_bf16.h>
#include <math.h>

#define WS_B 64
#define WS_S 197
#define WS_D 768
#define WS_NH 12
#define WS_L 12
#define WS_MLP 3072
#define WS_OUT 1000
#define WS_IND 768
#define WS_NPAT 196
#define SP 208      // S padded to 13*16
#define JP 224      // PV K-dim padded to 7*32

typedef __attribute__((ext_vector_type(8))) short bf16x8;
typedef __attribute__((ext_vector_type(4))) short s16x4;
typedef __attribute__((ext_vector_type(4))) float f32x4;

static __device__ __forceinline__ float bf2f(short s) {
    unsigned u = ((unsigned)(unsigned short)s) << 16;
    return __builtin_bit_cast(float, u);
}
static __device__ __forceinline__ short f2bf(float f) {
    unsigned u = __builtin_bit_cast(unsigned, f);
    u = (u + 0x7FFF + ((u >> 16) & 1)) >> 16;
    return (short)u;
}

// bijective XCD remap (m204): contiguous newid chunk per XCD
static __device__ __forceinline__ int xcd_remap(int wg, int nwg) {
    int q = nwg >> 3, r = nwg & 7;
    int xcd = wg & 7, idx = wg >> 3;
    return (xcd < r ? xcd * (q + 1) : r * (q + 1) + (xcd - r) * q) + idx;
}

// ------------------------------------------------- weight transpose to bf16
// W fp32 [L][K][N] row-major -> Wh bf16 [L][N][K]; layer = blockIdx.y
__global__ __launch_bounds__(256) void wconv_kernel(
    const float* __restrict__ W, short* __restrict__ Wh, int K, int N)
{
    const int l = blockIdx.y;
    const float* Wl = W + (size_t)l * K * N;
    short* Whl = Wh + (size_t)l * N * K;
    int idx = blockIdx.x * 256 + threadIdx.x;
    int total = (K >> 3) * N;
    if (idx >= total) return;
    int n = idx % N, k8 = idx / N, k0 = k8 << 3;
    short hi[8];
#pragma unroll
    for (int j = 0; j < 8; ++j) hi[j] = f2bf(Wl[(size_t)(k0 + j) * N + n]);
    *(bf16x8*)(Whl + (size_t)n * K + k0) = *(bf16x8*)hi;
}

// ------------------------------------------------- MFMA GEMM (bf16 in, fp32 acc)
// C[M,N] = act(A[M,K] @ B[K,N] + bias) (+ res) ; B stored [N][K] bf16
// Proven 5.84ms structure: 128^2 tile, 32KB single-buffer LDS, block TLP.
__global__ __launch_bounds__(256) void mfma_gemm(
    const short* __restrict__ A, int lda,
    const short* __restrict__ Bh,
    const float* __restrict__ bias, const float* __restrict__ res,
    float* __restrict__ outF, short* __restrict__ outH, int ldc,
    int M, int N, int K, int act)
{
    __shared__ short As[128 * 64];
    __shared__ short Bs[128 * 64];

    const int tid = threadIdx.x;
    const int w = tid >> 6, lane = tid & 63;
    const int nwg = gridDim.x * gridDim.y;
    int wg = blockIdx.y * gridDim.x + blockIdx.x;
    wg = xcd_remap(wg, nwg);
    const int bm = (wg / gridDim.x) * 128, bn = (wg % gridDim.x) * 128;
    const int wm = (w >> 1) * 64, wn = (w & 1) * 64;
    const int lr = lane & 15, lq = lane >> 4;

    f32x4 acc[4][4];
#pragma unroll
    for (int i = 0; i < 4; ++i)
#pragma unroll
        for (int j = 0; j < 4; ++j) acc[i][j] = (f32x4){0.f, 0.f, 0.f, 0.f};

    int aoff[2][4], boff[2][4];
#pragma unroll
    for (int ks = 0; ks < 2; ++ks)
#pragma unroll
        for (int f = 0; f < 4; ++f) {
            int r = wm + f * 16 + lr;
            aoff[ks][f] = r * 64 + (((ks * 4 + lq) ^ (lr & 7)) << 3);
            int rn = wn + f * 16 + lr;
            boff[ks][f] = rn * 64 + (((ks * 4 + lq) ^ (lr & 7)) << 3);
        }

    const short* gaB[4];
    const short* gbB[4];
    int ldsb[4];
#pragma unroll
    for (int i = 0; i < 4; ++i) {
        int chunk = w * 64 + i * 256 + lane;
        int row = chunk >> 3, c = chunk & 7;
        int cs = c ^ (row & 7);
        int arow = bm + row; if (arow >= M) arow = M - 1;
        gaB[i] = A + (size_t)arow * lda + cs * 8;
        gbB[i] = Bh + (size_t)(bn + row) * K + cs * 8;
        ldsb[i] = chunk * 8;
    }

    for (int k0 = 0; k0 < K; k0 += 64) {
#pragma unroll
        for (int i = 0; i < 4; ++i) {
            __builtin_amdgcn_global_load_lds(
                (const __attribute__((address_space(1))) void*)(gaB[i] + k0),
                (__attribute__((address_space(3))) void*)(As + ldsb[i]), 16, 0, 0);
            __builtin_amdgcn_global_load_lds(
                (const __attribute__((address_space(1))) void*)(gbB[i] + k0),
                (__attribute__((address_space(3))) void*)(Bs + ldsb[i]), 16, 0, 0);
        }
        asm volatile("s_waitcnt vmcnt(0)" ::: "memory");
        __syncthreads();

#pragma unroll
        for (int ks = 0; ks < 2; ++ks) {
            bf16x8 av[4], bv[4];
#pragma unroll
            for (int f = 0; f < 4; ++f) av[f] = *(const bf16x8*)&As[aoff[ks][f]];
#pragma unroll
            for (int f = 0; f < 4; ++f) bv[f] = *(const bf16x8*)&Bs[boff[ks][f]];
#pragma unroll
            for (int fm = 0; fm < 4; ++fm)
#pragma unroll
                for (int fn = 0; fn < 4; ++fn)
                    acc[fm][fn] = __builtin_amdgcn_mfma_f32_16x16x32_bf16(
                        av[fm], bv[fn], acc[fm][fn], 0, 0, 0);
        }
        __syncthreads();
    }

#pragma unroll
    for (int fm = 0; fm < 4; ++fm)
#pragma unroll
        for (int fn = 0; fn < 4; ++fn) {
            int gc = bn + wn + fn * 16 + lr;
            float bvs = bias ? bias[gc] : 0.f;
            int grb = bm + wm + fm * 16 + lq * 4;
#pragma unroll
            for (int r = 0; r < 4; ++r) {
                int gr = grb + r;
                if (gr >= M) continue;
                float v = acc[fm][fn][r] + bvs;
                if (act == 1) v = 0.5f * v * (1.f + erff(v * 0.70710678118654752440f));
                if (res) v += res[(size_t)gr * ldc + gc];
                if (outF) outF[(size_t)gr * ldc + gc] = v;
                else      outH[(size_t)gr * ldc + gc] = f2bf(v);
            }
        }
}

// ------------------------------------------------- 128x256 MFMA GEMM (high-intensity)
// 512 thr, 8 waves 1Mx4N? -> 2Mx4N: wm=(w>>2)*64, wn=(w&3)*64. 48KB LDS, 3 blocks/CU.
// bytes/FLOP = 1/85 (vs 1/64 for 128^2). Requires N % 256 == 0, K % 64 == 0.
__global__ __launch_bounds__(512) void mfma_gemm_n256(
    const short* __restrict__ A, int lda,
    const short* __restrict__ Bh,
    const float* __restrict__ bias, const float* __restrict__ res,
    float* __restrict__ outF, short* __restrict__ outH, int ldc,
    int M, int N, int K, int act)
{
    __shared__ short As[128 * 64];   // 16 KB
    __shared__ short Bs[256 * 64];   // 32 KB

    const int tid = threadIdx.x;
    const int w = tid >> 6, lane = tid & 63;
    const int nwg = gridDim.x * gridDim.y;
    int wg = blockIdx.y * gridDim.x + blockIdx.x;
    wg = xcd_remap(wg, nwg);
    const int bm = (wg / gridDim.x) * 128, bn = (wg % gridDim.x) * 256;
    const int wm = (w >> 2) * 64, wn = (w & 3) * 64;
    const int lr = lane & 15, lq = lane >> 4;

    f32x4 acc[4][4];
#pragma unroll
    for (int i = 0; i < 4; ++i)
#pragma unroll
        for (int j = 0; j < 4; ++j) acc[i][j] = (f32x4){0.f, 0.f, 0.f, 0.f};

    int aoff[2][4], boff[2][4];
#pragma unroll
    for (int ks = 0; ks < 2; ++ks)
#pragma unroll
        for (int f = 0; f < 4; ++f) {
            int r = wm + f * 16 + lr;
            aoff[ks][f] = r * 64 + (((ks * 4 + lq) ^ (lr & 7)) << 3);
            int rn = wn + f * 16 + lr;
            boff[ks][f] = rn * 64 + (((ks * 4 + lq) ^ (lr & 7)) << 3);
        }

    // staging: A = 1024 chunks (2/thread), B = 2048 chunks (4/thread)
    const short* gaB[2];
    int ldsbA[2];
#pragma unroll
    for (int i = 0; i < 2; ++i) {
        int chunk = i * 512 + tid;
        int row = chunk >> 3, c = chunk & 7;
        int cs = c ^ (row & 7);
        int arow = bm + row; if (arow >= M) arow = M - 1;
        gaB[i] = A + (size_t)arow * lda + cs * 8;
        ldsbA[i] = chunk * 8;
    }
    const short* gbB[4];
    int ldsbB[4];
#pragma unroll
    for (int i = 0; i < 4; ++i) {
        int chunk = i * 512 + tid;
        int row = chunk >> 3, c = chunk & 7;
        int cs = c ^ (row & 7);
        gbB[i] = Bh + (size_t)(bn + row) * K + cs * 8;
        ldsbB[i] = chunk * 8;
    }

    for (int k0 = 0; k0 < K; k0 += 64) {
#pragma unroll
        for (int i = 0; i < 2; ++i)
            __builtin_amdgcn_global_load_lds(
                (const __attribute__((address_space(1))) void*)(gaB[i] + k0),
                (__attribute__((address_space(3))) void*)(As + ldsbA[i]), 16, 0, 0);
#pragma unroll
        for (int i = 0; i < 4; ++i)
            __builtin_amdgcn_global_load_lds(
                (const __attribute__((address_space(1))) void*)(gbB[i] + k0),
                (__attribute__((address_space(3))) void*)(Bs + ldsbB[i]), 16, 0, 0);
        asm volatile("s_waitcnt vmcnt(0)" ::: "memory");
        __syncthreads();

#pragma unroll
        for (int ks = 0; ks < 2; ++ks) {
            bf16x8 av[4], bv[4];
#pragma unroll
            for (int f = 0; f < 4; ++f) av[f] = *(const bf16x8*)&As[aoff[ks][f]];
#pragma unroll
            for (int f = 0; f < 4; ++f) bv[f] = *(const bf16x8*)&Bs[boff[ks][f]];
#pragma unroll
            for (int fm = 0; fm < 4; ++fm)
#pragma unroll
                for (int fn = 0; fn < 4; ++fn)
                    acc[fm][fn] = __builtin_amdgcn_mfma_f32_16x16x32_bf16(
                        av[fm], bv[fn], acc[fm][fn], 0, 0, 0);
        }
        __syncthreads();
    }

#pragma unroll
    for (int fm = 0; fm < 4; ++fm)
#pragma unroll
        for (int fn = 0; fn < 4; ++fn) {
            int gc = bn + wn + fn * 16 + lr;
            float bvs = bias ? bias[gc] : 0.f;
            int grb = bm + wm + fm * 16 + lq * 4;
#pragma unroll
            for (int r = 0; r < 4; ++r) {
                int gr = grb + r;
                if (gr >= M) continue;
                float v = acc[fm][fn][r] + bvs;
                if (act == 1) v = 0.5f * v * (1.f + erff(v * 0.70710678118654752440f));
                if (res) v += res[(size_t)gr * ldc + gc];
                if (outF) outF[(size_t)gr * ldc + gc] = v;
                else      outH[(size_t)gr * ldc + gc] = f2bf(v);
            }
        }
}

// ------------------------------------------------- MFMA attention
// qkv bf16 [B*S][2304] (head h: q +h*192, k +h*192+64, v +h*192+128)
// o bf16 [B*S][768]
__global__ __launch_bounds__(256) void attn_kernel(
    const short* __restrict__ qkv, short* __restrict__ o)
{
    __shared__ short Qs[SP * 64];       // [q][64], chunk c stored at c^(q&7)
    __shared__ short Ks[SP * 64];       // [j][64], same swizzle
    __shared__ short Vt[64 * 256];      // [d][j(224 pad, stride 256)], chunk cj^(d&7)
    __shared__ short Ps[4][16 * 256];   // per-wave P[qr][j], chunk cj^(qr&7)

    const int bh = blockIdx.x;
    const int n = bh / WS_NH, h = bh % WS_NH;
    const short* base = qkv + (size_t)n * WS_S * 2304 + h * 192;
    const int tid = threadIdx.x;
    const int w = tid >> 6, lane = tid & 63;
    const int lr = lane & 15, lq = lane >> 4;

    // zero this wave's P buffer (covers j-pad 208..223)
    const bf16x8 z8 = {0, 0, 0, 0, 0, 0, 0, 0};
    for (int i = lane; i < 512; i += 64) *(bf16x8*)&Ps[w][i * 8] = z8;

    // stage Q, K (rows >=197 zeroed)
    for (int u = tid; u < SP * 8; u += 256) {
        int row = u >> 3, c = u & 7;
        int cs = c ^ (row & 7);
        bf16x8 vq = z8, vk = z8;
        if (row < WS_S) {
            const short* rp = base + (size_t)row * 2304;
            vq = *(const bf16x8*)(rp + cs * 8);
            vk = *(const bf16x8*)(rp + 64 + cs * 8);
        }
        *(bf16x8*)&Qs[row * 64 + c * 8] = vq;
        *(bf16x8*)&Ks[row * 64 + c * 8] = vk;
    }

    // stage V transposed: vectorized 16B row loads, transposed scalar LDS scatter
#pragma unroll
    for (int pass = 0; pass < 7; ++pass) {
        int r = pass * 32 + (tid >> 3);     // 0..223
        int c = tid & 7;
        bf16x8 v = z8;
        if (r < WS_S) v = *(const bf16x8*)(base + (size_t)r * 2304 + 128 + c * 8);
#pragma unroll
        for (int e = 0; e < 8; ++e) {
            int d = c * 8 + e;
            Vt[d * 256 + ((((r >> 3)) ^ (d & 7)) << 3) + (r & 7)] = v[e];
        }
    }
    __syncthreads();

    for (int qt = w; qt < 13; qt += 4) {
        // swapped QK^T: D = K·Q^T, lane owns q-col = qt*16+lr
        bf16x8 qv[2];
#pragma unroll
        for (int ks = 0; ks < 2; ++ks)
            qv[ks] = *(const bf16x8*)&Qs[(qt * 16 + lr) * 64 + (((ks * 4 + lq) ^ (lr & 7)) << 3)];
        f32x4 acc[13];
#pragma unroll
        for (int jt = 0; jt < 13; ++jt) acc[jt] = (f32x4){0.f, 0.f, 0.f, 0.f};
#pragma unroll
        for (int jt = 0; jt < 13; ++jt)
#pragma unroll
            for (int ks = 0; ks < 2; ++ks) {
                bf16x8 kv = *(const bf16x8*)&Ks[(jt * 16 + lr) * 64 + (((ks * 4 + lq) ^ (lr & 7)) << 3)];
                acc[jt] = __builtin_amdgcn_mfma_f32_16x16x32_bf16(kv, qv[ks], acc[jt], 0, 0, 0);
            }

        // softmax over j (lane-local 52 values + 2 shuffles across lq groups)
        float s[13][4];
        float m = -1e30f;
#pragma unroll
        for (int jt = 0; jt < 13; ++jt)
#pragma unroll
            for (int r = 0; r < 4; ++r) {
                int j = jt * 16 + lq * 4 + r;
                float v = acc[jt][r] * 0.125f;
                s[jt][r] = v;
                if (j < WS_S) m = fmaxf(m, v);
            }
        m = fmaxf(m, __shfl_xor(m, 16));
        m = fmaxf(m, __shfl_xor(m, 32));
        float sum = 0.f;
#pragma unroll
        for (int jt = 0; jt < 13; ++jt)
#pragma unroll
            for (int r = 0; r < 4; ++r) {
                int j = jt * 16 + lq * 4 + r;
                float e = (j < WS_S) ? __expf(s[jt][r] - m) : 0.f;
                s[jt][r] = e;
                sum += e;
            }
        sum += __shfl_xor(sum, 16);
        sum += __shfl_xor(sum, 32);
        float inv = (sum > 0.f) ? 1.f / sum : 0.f;

        // write P rows (q_local = lr), r-pairs packed as b32
#pragma unroll
        for (int jt = 0; jt < 13; ++jt) {
            int jb = jt * 16 + lq * 4;
            int cj = jb >> 3, e = jb & 7;
            int off = lr * 256 + ((cj ^ (lr & 7)) << 3) + e;
            unsigned p01 = (unsigned)(unsigned short)f2bf(s[jt][0] * inv) |
                           ((unsigned)(unsigned short)f2bf(s[jt][1] * inv) << 16);
            unsigned p23 = (unsigned)(unsigned short)f2bf(s[jt][2] * inv) |
                           ((unsigned)(unsigned short)f2bf(s[jt][3] * inv) << 16);
            *(unsigned*)&Ps[w][off] = p01;
            *(unsigned*)&Ps[w][off + 2] = p23;
        }
        __builtin_amdgcn_s_waitcnt(0);   // drain lds writes (within-wave)

        // PV: O = P @ V (K = 224)
        bf16x8 pa[7];
#pragma unroll
        for (int ks = 0; ks < 7; ++ks)
            pa[ks] = *(const bf16x8*)&Ps[w][lr * 256 + (((ks * 4 + lq) ^ (lr & 7)) << 3)];
#pragma unroll
        for (int dt = 0; dt < 4; ++dt) {
            f32x4 oacc = (f32x4){0.f, 0.f, 0.f, 0.f};
#pragma unroll
            for (int ks = 0; ks < 7; ++ks) {
                bf16x8 vb = *(const bf16x8*)&Vt[(dt * 16 + lr) * 256 + (((ks * 4 + lq) ^ (lr & 7)) << 3)];
                oacc = __builtin_amdgcn_mfma_f32_16x16x32_bf16(pa[ks], vb, oacc, 0, 0, 0);
            }
#pragma unroll
            for (int r = 0; r < 4; ++r) {
                int qg = qt * 16 + lq * 4 + r;
                if (qg < WS_S)
                    o[((size_t)n * WS_S + qg) * WS_D + h * 64 + dt * 16 + lr] = f2bf(oacc[r]);
            }
        }
    }
}

// ------------------------------------------------- head (fp32, latency-friendly)
__global__ __launch_bounds__(256) void head_kernel(
    const float* __restrict__ x, const float* __restrict__ W,
    const float* __restrict__ bias, float* __restrict__ out)
{
    int c = blockIdx.x * 16 + (threadIdx.x & 15);
    int m = blockIdx.y * 16 + (threadIdx.x >> 4);
    if (c >= WS_OUT) return;
    const float* xr = x + (size_t)m * (WS_S * WS_D);
    float acc = bias[c];
    for (int k = 0; k < WS_D; ++k)
        acc = fmaf(xr[k], W[(size_t)k * WS_OUT + c], acc);
    out[(size_t)m * WS_OUT + c] = acc;
}

// ------------------------------------------------- LayerNorm (wave-per-row, fp32 in, bf16 out)
__global__ __launch_bounds__(256) void ln_kernel(
    const float* __restrict__ x, const float* __restrict__ g,
    const float* __restrict__ b, short* __restrict__ y)
{
    const int row = blockIdx.x * 4 + (threadIdx.x >> 6);
    const int lane = threadIdx.x & 63;
    const float* xr = x + (size_t)row * WS_D;
    float4 v0 = *(const float4*)(xr + lane * 4);
    float4 v1 = *(const float4*)(xr + 256 + lane * 4);
    float4 v2 = *(const float4*)(xr + 512 + lane * 4);
    float s = v0.x + v0.y + v0.z + v0.w + v1.x + v1.y + v1.z + v1.w
            + v2.x + v2.y + v2.z + v2.w;
    float q = v0.x * v0.x + v0.y * v0.y + v0.z * v0.z + v0.w * v0.w
            + v1.x * v1.x + v1.y * v1.y + v1.z * v1.z + v1.w * v1.w
            + v2.x * v2.x + v2.y * v2.y + v2.z * v2.z + v2.w * v2.w;
#pragma unroll
    for (int off = 32; off > 0; off >>= 1) {
        s += __shfl_xor(s, off);
        q += __shfl_xor(q, off);
    }
    const float mean = s * (1.f / WS_D);
    const float var = q * (1.f / WS_D) - mean * mean;
    const float rstd = rsqrtf(var + 1e-5f);
    short* yr = y + (size_t)row * WS_D;
#pragma unroll
    for (int c = 0; c < 3; ++c) {
        int o = c * 256 + lane * 4;
        float4 v = (c == 0) ? v0 : (c == 1) ? v1 : v2;
        float4 gv = *(const float4*)(g + o);
        float4 bv = *(const float4*)(b + o);
        s16x4 ov;
        ov[0] = f2bf((v.x - mean) * rstd * gv.x + bv.x);
        ov[1] = f2bf((v.y - mean) * rstd * gv.y + bv.y);
        ov[2] = f2bf((v.z - mean) * rstd * gv.z + bv.z);
        ov[3] = f2bf((v.w - mean) * rstd * gv.w + bv.w);
        *(s16x4*)(yr + o) = ov;
    }
}

// ------------------------------------------------- small utils
__global__ void pe_kernel(float* __restrict__ pe)
{
    int idx = blockIdx.x * 256 + threadIdx.x;
    if (idx >= WS_S * WS_D) return;
    int s = idx / WS_D, j = idx % WS_D;
    float expo = (float)(j & ~1) / (float)WS_D;
    float angle = (float)s * powf(10000.f, -expo);
    pe[idx] = (j & 1) ? cosf(angle) : sinf(angle);
}

__global__ void patchify_kernel(const float* __restrict__ img, short* __restrict__ p)
{
    int idx = blockIdx.x * 256 + threadIdx.x;
    const int total = WS_B * WS_NPAT * WS_IND;
    if (idx >= total) return;
    int pid = idx / WS_IND;
    int e = idx % WS_IND;
    int n = pid / WS_NPAT, patch = pid % WS_NPAT;
    int c = e >> 8, r = e & 255;
    int iy = r >> 4, ix = r & 15;
    int py = patch / 14, px = patch % 14;
    p[idx] = f2bf(img[(((size_t)n * 3 + c) * 224 + py * 16 + iy) * 224 + px * 16 + ix]);
}

__global__ void assemble_kernel(const float* __restrict__ tok, const float* __restrict__ cls,
                                const float* __restrict__ pe, float* __restrict__ x)
{
    int idx = blockIdx.x * 256 + threadIdx.x;
    const int total = WS_B * WS_S * WS_D;
    if (idx >= total) return;
    int row = idx / WS_D, d = idx % WS_D;
    int n = row / WS_S, s = row % WS_S;
    float v = (s == 0) ? cls[d] : tok[((size_t)n * WS_NPAT + (s - 1)) * WS_D + d];
    x[idx] = v + pe[s * WS_D + d];
}

__global__ __launch_bounds__(256) void softmax1000_kernel(
    const float* __restrict__ logits, float* __restrict__ out)
{
    __shared__ float rmax[4], rsum[4];
    const int row = blockIdx.x;
    const int tid = threadIdx.x;
    const float* lr = logits + (size_t)row * WS_OUT;
    float v[4];
    float mx = -INFINITY;
#pragma unroll
    for (int i = 0; i < 4; ++i) {
        int c = tid + i * 256;
        v[i] = (c < WS_OUT) ? lr[c] : -INFINITY;
        mx = fmaxf(mx, v[i]);
    }
#pragma unroll
    for (int off = 32; off > 0; off >>= 1) mx = fmaxf(mx, __shfl_xor(mx, off));
    if ((tid & 63) == 0) rmax[tid >> 6] = mx;
    __syncthreads();
    mx = fmaxf(fmaxf(rmax[0], rmax[1]), fmaxf(rmax[2], rmax[3]));
    float sum = 0.f;
#pragma unroll
    for (int i = 0; i < 4; ++i) {
        int c = tid + i * 256;
        v[i] = (c < WS_OUT) ? expf(v[i] - mx) : 0.f;
        sum += v[i];
    }
#pragma unroll
    for (int off = 32; off > 0; off >>= 1) sum += __shfl_xor(sum, off);
    if ((tid & 63) == 0) rsum[tid >> 6] = sum;
    __syncthreads();
    sum = rsum[0] + rsum[1] + rsum[2] + rsum[3];
    const float inv = 1.f / sum;
#pragma unroll
    for (int i = 0; i < 4; ++i) {
        int c = tid + i * 256;
        if (c < WS_OUT) out[(size_t)row * WS_OUT + c] = v[i] * inv;
    }
}

// ------------------------------------------------- launch
extern "C" void kernel_launch(void* const* d_in, const int* in_sizes, int n_in,
                              void* d_out, int out_size, void* d_ws, size_t ws_size,
                              hipStream_t stream)
{
    const float* images = (const float*)d_in[0];
    const float* lm_w   = (const float*)d_in[1];
    const float* lm_b   = (const float*)d_in[2];
    const float* cls    = (const float*)d_in[3];
    const float* ln1_g  = (const float*)d_in[4];
    const float* ln1_b  = (const float*)d_in[5];
    const float* qkv_w  = (const float*)d_in[6];
    const float* qkv_b  = (const float*)d_in[7];
    const float* out_w  = (const float*)d_in[8];
    const float* out_b  = (const float*)d_in[9];
    const float* ln2_g  = (const float*)d_in[10];
    const float* ln2_b  = (const float*)d_in[11];
    const float* mlp1_w = (const float*)d_in[12];
    const float* mlp1_b = (const float*)d_in[13];
    const float* mlp2_w = (const float*)d_in[14];
    const float* mlp2_b = (const float*)d_in[15];
    const float* head_w = (const float*)d_in[16];
    const float* head_b = (const float*)d_in[17];

    const int ROWS = WS_B * WS_S;          // 12608 = 197*64
    char* wsb = (char*)d_ws;
    size_t off = 0;
    auto alloc = [&](size_t bytes) {
        void* p = wsb + off;
        off += (bytes + 255) & ~(size_t)255;
        return p;
    };
    float* pe     = (float*)alloc((size_t)WS_S * WS_D * 4);
    float* x      = (float*)alloc((size_t)ROWS * WS_D * 4);
    short* xh     = (short*)alloc((size_t)ROWS * WS_D * 2);
    short* qkvh   = (short*)alloc((size_t)ROWS * 2304 * 2);
    short* oh     = (short*)alloc((size_t)ROWS * WS_D * 2);
    short* hh     = (short*)alloc((size_t)ROWS * WS_MLP * 2);
    float* logits = (float*)alloc((size_t)WS_B * WS_OUT * 4);
    short* ph     = (short*)alloc((size_t)WS_B * WS_NPAT * WS_IND * 2);
    // all-layer converted weights (bf16, [N][K] per layer)
    short* qW_all  = (short*)alloc((size_t)WS_L * WS_D * 2304 * 2);
    short* oW_all  = (short*)alloc((size_t)WS_L * WS_D * WS_D * 2);
    short* m1W_all = (short*)alloc((size_t)WS_L * WS_D * WS_MLP * 2);
    short* m2W_all = (short*)alloc((size_t)WS_L * WS_MLP * WS_D * 2);
    short* lmWh    = (short*)alloc((size_t)WS_IND * WS_D * 2);
    float* tok  = (float*)hh;   // overlay (pre-loop only): 38.5 MB < hh

    pe_kernel<<<(WS_S * WS_D + 255) / 256, 256, 0, stream>>>(pe);
    patchify_kernel<<<(WS_B * WS_NPAT * WS_IND + 255) / 256, 256, 0, stream>>>(images, ph);
    // one-time conversion of ALL weights
    wconv_kernel<<<dim3((WS_IND / 8 * WS_D + 255) / 256, 1), 256, 0, stream>>>(lm_w, lmWh, WS_IND, WS_D);
    wconv_kernel<<<dim3((WS_D / 8 * 2304 + 255) / 256, WS_L), 256, 0, stream>>>(qkv_w, qW_all, WS_D, 2304);
    wconv_kernel<<<dim3((WS_D / 8 * WS_D + 255) / 256, WS_L), 256, 0, stream>>>(out_w, oW_all, WS_D, WS_D);
    wconv_kernel<<<dim3((WS_D / 8 * WS_MLP + 255) / 256, WS_L), 256, 0, stream>>>(mlp1_w, m1W_all, WS_D, WS_MLP);
    wconv_kernel<<<dim3((WS_MLP / 8 * WS_D + 255) / 256, WS_L), 256, 0, stream>>>(mlp2_w, m2W_all, WS_MLP, WS_D);

    // tok = patches @ lm_w + lm_b  (M=12544, N=768, K=768)
    mfma_gemm<<<dim3(6, 98), 256, 0, stream>>>(
        ph, WS_IND, lmWh, lm_b, nullptr, tok, nullptr, WS_D,
        WS_B * WS_NPAT, WS_D, WS_IND, 0);
    assemble_kernel<<<(WS_B * WS_S * WS_D + 255) / 256, 256, 0, stream>>>(tok, cls, pe, x);

    for (int l = 0; l < WS_L; ++l) {
        ln_kernel<<<ROWS / 4, 256, 0, stream>>>(x, ln1_g + l * WS_D, ln1_b + l * WS_D, xh);
        mfma_gemm_n256<<<dim3(9, 99), 512, 0, stream>>>(
            xh, WS_D, qW_all + (size_t)l * WS_D * 2304, qkv_b + l * 2304,
            nullptr, nullptr, qkvh, 2304, ROWS, 2304, WS_D, 0);
        attn_kernel<<<WS_B * WS_NH, 256, 0, stream>>>(qkvh, oh);
        mfma_gemm<<<dim3(6, 99), 256, 0, stream>>>(
            oh, WS_D, oW_all + (size_t)l * WS_D * WS_D, out_b + l * WS_D,
            x, x, nullptr, WS_D, ROWS, WS_D, WS_D, 0);
        ln_kernel<<<ROWS / 4, 256, 0, stream>>>(x, ln2_g + l * WS_D, ln2_b + l * WS_D, xh);
        mfma_gemm_n256<<<dim3(12, 99), 512, 0, stream>>>(
            xh, WS_D, m1W_all + (size_t)l * WS_D * WS_MLP, mlp1_b + l * WS_MLP,
            nullptr, nullptr, hh, WS_MLP, ROWS, WS_MLP, WS_D, 1);
        mfma_gemm<<<dim3(6, 99), 256, 0, stream>>>(
            hh, WS_MLP, m2W_all + (size_t)l * WS_MLP * WS_D, mlp2_b + l * WS_D,
            x, x, nullptr, WS_D, ROWS, WS_D, WS_MLP, 0);
    }

    head_kernel<<<dim3((WS_OUT + 15) / 16, 4), 256, 0, stream>>>(x, head_w, head_b, logits);
    softmax1000_kernel<<<WS_B, 256, 0, stream>>>(logits, (float*)d_out);
}